// Round 2
// baseline (786.937 us; speedup 1.0000x reference)
//
#include <hip/hip_runtime.h>

typedef __bf16 bf16;
typedef __attribute__((ext_vector_type(4))) float f32x4;
typedef __attribute__((ext_vector_type(8))) __bf16 bf16x8;
typedef __attribute__((ext_vector_type(4))) __bf16 bf16x4;

#define HIDDEN 2048
#define L_SEQ 2048
#define NHEADS 8
#define NKV 4
#define HDIM 256

// ---------------- fp32 -> bf16 cast (vectorized) ----------------
__global__ __launch_bounds__(256) void cast_bf16_kernel(const float* __restrict__ in,
                                                        bf16* __restrict__ out, int n4) {
  int i = blockIdx.x * 256 + threadIdx.x;
  if (i >= n4) return;
  float4 v = ((const float4*)in)[i];
  bf16x4 o;
  o[0] = (bf16)v.x; o[1] = (bf16)v.y; o[2] = (bf16)v.z; o[3] = (bf16)v.w;
  ((bf16x4*)out)[i] = o;
}

// ---------------- GEMM: C[m][n] = sum_k A[m][k] * B[n][k] ----------------
// A: M x K bf16 row-major, B: N x K bf16 row-major (i.e. computes A @ B^T)
// 128x128 tile, BK=64, 4 waves (2x2), XOR-swizzled LDS, 16x16x32 bf16 MFMA.
template <int OUT_BF16>
__global__ __launch_bounds__(256) void gemm_bt(const bf16* __restrict__ A,
                                               const bf16* __restrict__ B,
                                               void* __restrict__ C,
                                               int M, int N, int K) {
  __shared__ __attribute__((aligned(16))) bf16 As[128 * 64];
  __shared__ __attribute__((aligned(16))) bf16 Bs[128 * 64];
  const int tid = threadIdx.x;
  const int lane = tid & 63;
  const int wid = tid >> 6;
  const int m0 = blockIdx.y * 128;
  const int n0 = blockIdx.x * 128;
  const int wm = (wid >> 1) * 64;
  const int wn = (wid & 1) * 64;

  f32x4 acc[4][4];
#pragma unroll
  for (int i = 0; i < 4; ++i)
#pragma unroll
    for (int j = 0; j < 4; ++j) acc[i][j] = (f32x4){0.f, 0.f, 0.f, 0.f};

  for (int k0 = 0; k0 < K; k0 += 64) {
    __syncthreads();
    // stage 128x64 A-tile and B-tile, XOR swizzle (row&7)<<4 on byte column
#pragma unroll
    for (int c = 0; c < 4; ++c) {
      int idx = c * 256 + tid;
      int row = idx >> 3;
      int colb = (idx & 7) * 16;
      int swz = colb ^ ((row & 7) << 4);
      *(int4*)((char*)As + row * 128 + swz) =
          *(const int4*)(A + (size_t)(m0 + row) * K + k0 + (idx & 7) * 8);
      *(int4*)((char*)Bs + row * 128 + swz) =
          *(const int4*)(B + (size_t)(n0 + row) * K + k0 + (idx & 7) * 8);
    }
    __syncthreads();
#pragma unroll
    for (int kk = 0; kk < 2; ++kk) {
      bf16x8 a[4], b[4];
      int colb = kk * 64 + (lane >> 4) * 16;
#pragma unroll
      for (int i = 0; i < 4; ++i) {
        int row = wm + i * 16 + (lane & 15);
        a[i] = *(const bf16x8*)((const char*)As + row * 128 + (colb ^ ((row & 7) << 4)));
      }
#pragma unroll
      for (int j = 0; j < 4; ++j) {
        int row = wn + j * 16 + (lane & 15);
        b[j] = *(const bf16x8*)((const char*)Bs + row * 128 + (colb ^ ((row & 7) << 4)));
      }
#pragma unroll
      for (int i = 0; i < 4; ++i)
#pragma unroll
        for (int j = 0; j < 4; ++j)
          acc[i][j] = __builtin_amdgcn_mfma_f32_16x16x32_bf16(a[i], b[j], acc[i][j], 0, 0, 0);
    }
  }
  // epilogue: C/D layout col = lane&15, row = (lane>>4)*4 + r
#pragma unroll
  for (int i = 0; i < 4; ++i)
#pragma unroll
    for (int j = 0; j < 4; ++j)
#pragma unroll
      for (int r = 0; r < 4; ++r) {
        int m = m0 + wm + i * 16 + ((lane >> 4) << 2) + r;
        int n = n0 + wn + j * 16 + (lane & 15);
        float v = acc[i][j][r];
        if (OUT_BF16)
          ((bf16*)C)[(size_t)m * N + n] = (bf16)v;
        else
          ((float*)C)[(size_t)m * N + n] = v;
      }
}

// ---------------- per-head RMSNorm + relayout ----------------
// qkv: [4096][4096] bf16 rows = (b,l); cols: [0,2048) q heads, [2048,3072) k, [3072,4096) v
// Q: [B][H][L][D], K: [B][KV][L][D], Vt: [B][KV][D][L]
__global__ __launch_bounds__(256) void qknorm_kernel(const bf16* __restrict__ qkv,
                                                     const float* __restrict__ qnw,
                                                     const float* __restrict__ knw,
                                                     bf16* __restrict__ Q,
                                                     bf16* __restrict__ K,
                                                     bf16* __restrict__ Vt) {
  int w = threadIdx.x >> 6, lane = threadIdx.x & 63;
  int vec = blockIdx.x * 4 + w;          // 65536 head-vectors
  int row = vec >> 4, sub = vec & 15;    // 16 vectors per (b,l) row
  int b = row >> 11, l = row & 2047;
  const bf16* src = qkv + (size_t)row * 4096 + sub * 256 + lane * 4;
  bf16x4 v = *(const bf16x4*)src;
  float f[4];
#pragma unroll
  for (int j = 0; j < 4; ++j) f[j] = (float)v[j];

  if (sub < 12) {
    float ss = f[0] * f[0] + f[1] * f[1] + f[2] * f[2] + f[3] * f[3];
#pragma unroll
    for (int off = 1; off < 64; off <<= 1) ss += __shfl_xor(ss, off);
    float rs = rsqrtf(ss * (1.0f / 256.0f) + 1e-6f);
    if (sub < 8) {
      rs *= 0.0625f;  // fold attention scale 1/sqrt(256) into q
      bf16x4 o;
#pragma unroll
      for (int j = 0; j < 4; ++j) o[j] = (bf16)(f[j] * rs * qnw[lane * 4 + j]);
      *(bf16x4*)(Q + ((size_t)(b * 8 + sub) * 2048 + l) * 256 + lane * 4) = o;
    } else {
      bf16x4 o;
#pragma unroll
      for (int j = 0; j < 4; ++j) o[j] = (bf16)(f[j] * rs * knw[lane * 4 + j]);
      *(bf16x4*)(K + ((size_t)(b * 4 + (sub - 8)) * 2048 + l) * 256 + lane * 4) = o;
    }
  } else {
    // V: plain copy, transposed to [d][l]
    bf16* dst = Vt + (size_t)(b * 4 + (sub - 12)) * 256 * 2048 + l;
#pragma unroll
    for (int j = 0; j < 4; ++j) dst[(size_t)(lane * 4 + j) * 2048] = v[j];
  }
}

// ---------------- flash attention (causal, GQA) ----------------
// grid: B*H*(L/64) blocks, 4 waves; wave w owns q rows [qt*64+w*16, +16), D=256.
__global__ __launch_bounds__(256) void attn_kernel(const bf16* __restrict__ Q,
                                                   const bf16* __restrict__ K,
                                                   const bf16* __restrict__ Vt,
                                                   bf16* __restrict__ Out) {
  __shared__ __attribute__((aligned(16))) bf16 Plds[4][16][72];  // +8 pad: conflict-free
  const int lane = threadIdx.x & 63;
  const int w = threadIdx.x >> 6;
  const int bid = blockIdx.x;
  const int qt = bid & 31;
  const int h = (bid >> 5) & 7;
  const int b = bid >> 8;
  const int kh = h >> 1;
  const int q0 = qt * 64 + w * 16;
  const int l15 = lane & 15;
  const int l4 = lane >> 4;
  const int koff = l4 * 8;

  const bf16* Qp = Q + ((size_t)(b * 8 + h) * 2048 + q0) * 256;
  const bf16* Kp = K + (size_t)(b * 4 + kh) * 2048 * 256;
  const bf16* Vp = Vt + (size_t)(b * 4 + kh) * 256 * 2048;

  // Q fragments: 16 rows x 256, A-layout (row=lane&15, k contiguous 8 at (lane>>4)*8)
  bf16x8 qf[8];
#pragma unroll
  for (int c = 0; c < 8; ++c) qf[c] = *(const bf16x8*)(Qp + (size_t)l15 * 256 + c * 32 + koff);

  f32x4 o[16];
#pragma unroll
  for (int dt = 0; dt < 16; ++dt) o[dt] = (f32x4){0.f, 0.f, 0.f, 0.f};
  float mrow[4], lrow[4];
#pragma unroll
  for (int r = 0; r < 4; ++r) { mrow[r] = -__builtin_inff(); lrow[r] = 0.f; }

  const int nkb = qt + 1;
  for (int kb = 0; kb < nkb; ++kb) {
    // S = Q K^T : 16 q x 64 keys
    f32x4 s[4];
#pragma unroll
    for (int kt = 0; kt < 4; ++kt) s[kt] = (f32x4){0.f, 0.f, 0.f, 0.f};
#pragma unroll
    for (int kt = 0; kt < 4; ++kt) {
      const bf16* kbase = Kp + (size_t)(kb * 64 + kt * 16 + l15) * 256 + koff;
#pragma unroll
      for (int kk = 0; kk < 8; ++kk) {
        bf16x8 kf = *(const bf16x8*)(kbase + kk * 32);
        s[kt] = __builtin_amdgcn_mfma_f32_16x16x32_bf16(qf[kk], kf, s[kt], 0, 0, 0);
      }
    }
    if (kb == qt) {  // diagonal block: causal mask
#pragma unroll
      for (int kt = 0; kt < 4; ++kt) {
        int key = kb * 64 + kt * 16 + l15;
#pragma unroll
        for (int r = 0; r < 4; ++r) {
          int qg = q0 + (l4 << 2) + r;
          if (key > qg) s[kt][r] = -__builtin_inff();
        }
      }
    }
    // online softmax (rows live on 16-lane groups; reduce over lane&15)
    float mnew[4], scl[4], rsum[4];
#pragma unroll
    for (int r = 0; r < 4; ++r) {
      float rm = fmaxf(fmaxf(s[0][r], s[1][r]), fmaxf(s[2][r], s[3][r]));
#pragma unroll
      for (int off = 1; off < 16; off <<= 1) rm = fmaxf(rm, __shfl_xor(rm, off));
      mnew[r] = fmaxf(mrow[r], rm);
      scl[r] = __expf(mrow[r] - mnew[r]);
      rsum[r] = 0.f;
    }
#pragma unroll
    for (int kt = 0; kt < 4; ++kt)
#pragma unroll
      for (int r = 0; r < 4; ++r) {
        float p = __expf(s[kt][r] - mnew[r]);
        s[kt][r] = p;
        rsum[r] += p;
      }
#pragma unroll
    for (int r = 0; r < 4; ++r) {
#pragma unroll
      for (int off = 1; off < 16; off <<= 1) rsum[r] += __shfl_xor(rsum[r], off);
      lrow[r] = lrow[r] * scl[r] + rsum[r];
      mrow[r] = mnew[r];
    }
#pragma unroll
    for (int dt = 0; dt < 16; ++dt)
#pragma unroll
      for (int r = 0; r < 4; ++r) o[dt][r] *= scl[r];
    // P (D-layout) -> LDS -> A-layout fragments
#pragma unroll
    for (int kt = 0; kt < 4; ++kt)
#pragma unroll
      for (int r = 0; r < 4; ++r)
        Plds[w][(l4 << 2) + r][kt * 16 + l15] = (bf16)s[kt][r];
    bf16x8 pa[2];
#pragma unroll
    for (int kk2 = 0; kk2 < 2; ++kk2)
      pa[kk2] = *(const bf16x8*)&Plds[w][l15][kk2 * 32 + koff];
    // O += P V  (V fragments contiguous thanks to Vt layout)
#pragma unroll
    for (int dt = 0; dt < 16; ++dt) {
      const bf16* vbase = Vp + (size_t)(dt * 16 + l15) * 2048 + kb * 64 + koff;
#pragma unroll
      for (int kk2 = 0; kk2 < 2; ++kk2) {
        bf16x8 vf = *(const bf16x8*)(vbase + kk2 * 32);
        o[dt] = __builtin_amdgcn_mfma_f32_16x16x32_bf16(pa[kk2], vf, o[dt], 0, 0, 0);
      }
    }
  }
  // epilogue: divide by l, write [b*L + q][h*256 + d] bf16
  float rcp[4];
#pragma unroll
  for (int r = 0; r < 4; ++r) rcp[r] = 1.0f / lrow[r];
#pragma unroll
  for (int dt = 0; dt < 16; ++dt)
#pragma unroll
    for (int r = 0; r < 4; ++r) {
      int qg = q0 + (l4 << 2) + r;
      Out[(size_t)(b * 2048 + qg) * 2048 + h * 256 + dt * 16 + l15] =
          (bf16)(o[dt][r] * rcp[r]);
    }
}

// ---------------- launch ----------------
extern "C" void kernel_launch(void* const* d_in, const int* in_sizes, int n_in,
                              void* d_out, int out_size, void* d_ws, size_t ws_size,
                              hipStream_t stream) {
  const float* hidden = (const float*)d_in[0];
  const float* q_w = (const float*)d_in[1];
  const float* k_w = (const float*)d_in[2];
  const float* v_w = (const float*)d_in[3];
  const float* o_w = (const float*)d_in[4];
  const float* qnw = (const float*)d_in[5];
  const float* knw = (const float*)d_in[6];

  char* ws = (char*)d_ws;
  const size_t MB = (size_t)1 << 20;
  bf16* h_bf  = (bf16*)(ws + 0 * MB);    // 16 MiB  [4096][2048]
  bf16* wqkv  = (bf16*)(ws + 16 * MB);   // 16 MiB  [4096][2048] (q,k,v stacked)
  bf16* wo    = (bf16*)(ws + 32 * MB);   // 8 MiB   [2048][2048]
  bf16* qkv   = (bf16*)(ws + 40 * MB);   // 32 MiB  [4096][4096]
  bf16* aout  = qkv;                     // reuse (qkv dead after qknorm): [4096][2048]
  bf16* Qb    = (bf16*)(ws + 72 * MB);   // 16 MiB
  bf16* Kb    = (bf16*)(ws + 88 * MB);   // 8 MiB
  bf16* Vt    = (bf16*)(ws + 96 * MB);   // 8 MiB

  // casts (sizes in float4 units)
  cast_bf16_kernel<<<8192, 256, 0, stream>>>(hidden, h_bf, 2097152);
  cast_bf16_kernel<<<4096, 256, 0, stream>>>(q_w, wqkv, 1048576);
  cast_bf16_kernel<<<2048, 256, 0, stream>>>(k_w, wqkv + (size_t)2048 * 2048, 524288);
  cast_bf16_kernel<<<2048, 256, 0, stream>>>(v_w, wqkv + (size_t)3072 * 2048, 524288);
  cast_bf16_kernel<<<4096, 256, 0, stream>>>(o_w, wo, 1048576);

  // QKV projection: [4096][4096] = h_bf @ wqkv^T
  gemm_bt<1><<<dim3(32, 32), 256, 0, stream>>>(h_bf, wqkv, qkv, 4096, 4096, 2048);

  // RMSNorm q/k + relayout + V transpose
  qknorm_kernel<<<16384, 256, 0, stream>>>(qkv, qnw, knw, Qb, Kb, Vt);

  // causal GQA flash attention
  attn_kernel<<<512, 256, 0, stream>>>(Qb, Kb, Vt, aout);

  // output projection: fp32 out = aout @ wo^T
  gemm_bt<0><<<dim3(16, 32), 256, 0, stream>>>(aout, wo, d_out, 4096, 2048, 2048);
}

// Round 4
// 779.977 us; speedup vs baseline: 1.0089x; 1.0089x over previous
//
#include <hip/hip_runtime.h>

typedef __bf16 bf16;
typedef __attribute__((ext_vector_type(4))) float f32x4;
typedef __attribute__((ext_vector_type(8))) __bf16 bf16x8;
typedef __attribute__((ext_vector_type(4))) __bf16 bf16x4;

#define HIDDEN 2048
#define L_SEQ 2048
#define NHEADS 8
#define NKV 4
#define HDIM 256

// async global->LDS 16B (dest must be linear: wave-uniform base + lane*16)
__device__ __forceinline__ void gload16(const bf16* g, void* l) {
  __builtin_amdgcn_global_load_lds((const __attribute__((address_space(1))) void*)g,
                                   (__attribute__((address_space(3))) void*)l, 16, 0, 0);
}

// ---------------- fp32 -> bf16 cast (vectorized) ----------------
__global__ __launch_bounds__(256) void cast_bf16_kernel(const float* __restrict__ in,
                                                        bf16* __restrict__ out, int n4) {
  int i = blockIdx.x * 256 + threadIdx.x;
  if (i >= n4) return;
  float4 v = ((const float4*)in)[i];
  bf16x4 o;
  o[0] = (bf16)v.x; o[1] = (bf16)v.y; o[2] = (bf16)v.z; o[3] = (bf16)v.w;
  ((bf16x4*)out)[i] = o;
}

// ---------------- GEMM: C = A @ B^T ----------------
// 128x128 tile, BK=64, 4 waves, global_load_lds staging (linear LDS dest,
// pre-swizzled global source; reads apply XOR swizzle (row&7)<<4).
template <int OUT_BF16>
__global__ __launch_bounds__(256) void gemm_bt(const bf16* __restrict__ A,
                                               const bf16* __restrict__ B,
                                               void* __restrict__ C,
                                               int M, int N, int K) {
  __shared__ __attribute__((aligned(16))) bf16 As[128 * 64];
  __shared__ __attribute__((aligned(16))) bf16 Bs[128 * 64];
  const int tid = threadIdx.x;
  const int lane = tid & 63;
  const int wid = tid >> 6;
  const int m0 = blockIdx.y * 128;
  const int n0 = blockIdx.x * 128;
  const int wm = (wid >> 1) * 64;
  const int wn = (wid & 1) * 64;

  // staging geometry: idx = c*256+tid covers (row = idx>>3, 16B chunk idx&7)
  const int srow = tid >> 3;             // + c*32 per iteration
  const int scolb = (tid & 7) * 16;      // linear LDS byte column

  f32x4 acc[4][4];
#pragma unroll
  for (int i = 0; i < 4; ++i)
#pragma unroll
    for (int j = 0; j < 4; ++j) acc[i][j] = (f32x4){0.f, 0.f, 0.f, 0.f};

  for (int k0 = 0; k0 < K; k0 += 64) {
    __syncthreads();
#pragma unroll
    for (int c = 0; c < 4; ++c) {
      int row = c * 32 + srow;
      // linear LDS slot (row, scolb) must hold global column (scolb ^ swz(row))
      int gcol = (scolb ^ ((row & 7) << 4)) >> 1;  // bytes -> elements
      gload16(A + (size_t)(m0 + row) * K + k0 + gcol, (char*)As + row * 128 + scolb);
      gload16(B + (size_t)(n0 + row) * K + k0 + gcol, (char*)Bs + row * 128 + scolb);
    }
    __syncthreads();  // drains vmcnt (staged data visible)
#pragma unroll
    for (int kk = 0; kk < 2; ++kk) {
      bf16x8 a[4], b[4];
      int colb = kk * 64 + (lane >> 4) * 16;
#pragma unroll
      for (int i = 0; i < 4; ++i) {
        int row = wm + i * 16 + (lane & 15);
        a[i] = *(const bf16x8*)((const char*)As + row * 128 + (colb ^ ((row & 7) << 4)));
      }
#pragma unroll
      for (int j = 0; j < 4; ++j) {
        int row = wn + j * 16 + (lane & 15);
        b[j] = *(const bf16x8*)((const char*)Bs + row * 128 + (colb ^ ((row & 7) << 4)));
      }
#pragma unroll
      for (int i = 0; i < 4; ++i)
#pragma unroll
        for (int j = 0; j < 4; ++j)
          acc[i][j] = __builtin_amdgcn_mfma_f32_16x16x32_bf16(a[i], b[j], acc[i][j], 0, 0, 0);
    }
  }
  // epilogue: C/D layout col = lane&15, row = (lane>>4)*4 + r
#pragma unroll
  for (int i = 0; i < 4; ++i)
#pragma unroll
    for (int j = 0; j < 4; ++j)
#pragma unroll
      for (int r = 0; r < 4; ++r) {
        int m = m0 + wm + i * 16 + ((lane >> 4) << 2) + r;
        int n = n0 + wn + j * 16 + (lane & 15);
        float v = acc[i][j][r];
        if (OUT_BF16)
          ((bf16*)C)[(size_t)m * N + n] = (bf16)v;
        else
          ((float*)C)[(size_t)m * N + n] = v;
      }
}

// ---------------- per-head RMSNorm + relayout ----------------
__global__ __launch_bounds__(256) void qknorm_kernel(const bf16* __restrict__ qkv,
                                                     const float* __restrict__ qnw,
                                                     const float* __restrict__ knw,
                                                     bf16* __restrict__ Q,
                                                     bf16* __restrict__ K,
                                                     bf16* __restrict__ Vt) {
  int w = threadIdx.x >> 6, lane = threadIdx.x & 63;
  int vec = blockIdx.x * 4 + w;          // 65536 head-vectors
  int row = vec >> 4, sub = vec & 15;    // 16 vectors per (b,l) row
  int b = row >> 11, l = row & 2047;
  const bf16* src = qkv + (size_t)row * 4096 + sub * 256 + lane * 4;
  bf16x4 v = *(const bf16x4*)src;
  float f[4];
#pragma unroll
  for (int j = 0; j < 4; ++j) f[j] = (float)v[j];

  if (sub < 12) {
    float ss = f[0] * f[0] + f[1] * f[1] + f[2] * f[2] + f[3] * f[3];
#pragma unroll
    for (int off = 1; off < 64; off <<= 1) ss += __shfl_xor(ss, off);
    float rs = rsqrtf(ss * (1.0f / 256.0f) + 1e-6f);
    if (sub < 8) {
      rs *= 0.0625f;  // fold attention scale 1/sqrt(256) into q
      bf16x4 o;
#pragma unroll
      for (int j = 0; j < 4; ++j) o[j] = (bf16)(f[j] * rs * qnw[lane * 4 + j]);
      *(bf16x4*)(Q + ((size_t)(b * 8 + sub) * 2048 + l) * 256 + lane * 4) = o;
    } else {
      bf16x4 o;
#pragma unroll
      for (int j = 0; j < 4; ++j) o[j] = (bf16)(f[j] * rs * knw[lane * 4 + j]);
      *(bf16x4*)(K + ((size_t)(b * 4 + (sub - 8)) * 2048 + l) * 256 + lane * 4) = o;
    }
  } else {
    bf16* dst = Vt + (size_t)(b * 4 + (sub - 12)) * 256 * 2048 + l;
#pragma unroll
    for (int j = 0; j < 4; ++j) dst[(size_t)(lane * 4 + j) * 2048] = v[j];
  }
}

// ---------------- flash attention (causal, GQA) ----------------
// grid: B*H*128 one-wave blocks; block owns 16 q rows. VGPR-rich (grid only
// supplies 8 waves/CU, so up to 256 VGPR is free) -> deep load batching.
__global__ __launch_bounds__(64, 2) void attn_kernel(const bf16* __restrict__ Q,
                                                     const bf16* __restrict__ K,
                                                     const bf16* __restrict__ Vt,
                                                     bf16* __restrict__ Out) {
  __shared__ __attribute__((aligned(16))) bf16 Plds[16][72];
  const int lane = threadIdx.x;
  const int bid = blockIdx.x;
  const int tile = bid & 127;
  const int h = (bid >> 7) & 7;
  const int b = bid >> 10;
  const int kh = h >> 1;
  const int q0 = tile * 16;
  const int l15 = lane & 15;
  const int l4 = lane >> 4;
  const int koff = l4 * 8;

  const bf16* Qp = Q + ((size_t)(b * 8 + h) * 2048 + q0) * 256;
  const bf16* Kp = K + (size_t)(b * 4 + kh) * 2048 * 256;
  const bf16* Vp = Vt + (size_t)(b * 4 + kh) * 256 * 2048;

  bf16x8 qf[8];
#pragma unroll
  for (int c = 0; c < 8; ++c) qf[c] = *(const bf16x8*)(Qp + (size_t)l15 * 256 + c * 32 + koff);

  f32x4 o[16];
#pragma unroll
  for (int dt = 0; dt < 16; ++dt) o[dt] = (f32x4){0.f, 0.f, 0.f, 0.f};
  float mrow[4], lrow[4];
#pragma unroll
  for (int r = 0; r < 4; ++r) { mrow[r] = -__builtin_inff(); lrow[r] = 0.f; }

  const int nkb = (tile >> 2) + 1;
  for (int kb = 0; kb < nkb; ++kb) {
    // ---- S = Q K^T : 16 q x 64 keys (batched loads per kt) ----
    f32x4 s[4];
#pragma unroll
    for (int kt = 0; kt < 4; ++kt) s[kt] = (f32x4){0.f, 0.f, 0.f, 0.f};
#pragma unroll
    for (int kt = 0; kt < 4; ++kt) {
      const bf16* kbase = Kp + (size_t)(kb * 64 + kt * 16 + l15) * 256 + koff;
      bf16x8 kf[8];
#pragma unroll
      for (int kk = 0; kk < 8; ++kk) kf[kk] = *(const bf16x8*)(kbase + kk * 32);
#pragma unroll
      for (int kk = 0; kk < 8; ++kk)
        s[kt] = __builtin_amdgcn_mfma_f32_16x16x32_bf16(qf[kk], kf[kk], s[kt], 0, 0, 0);
    }
    if (kb == nkb - 1) {  // diagonal block: causal mask
#pragma unroll
      for (int kt = 0; kt < 4; ++kt) {
        int key = kb * 64 + kt * 16 + l15;
#pragma unroll
        for (int r = 0; r < 4; ++r) {
          int qg = q0 + (l4 << 2) + r;
          if (key > qg) s[kt][r] = -__builtin_inff();
        }
      }
    }
    // ---- online softmax with defer-max (T13) ----
    float rm[4];
#pragma unroll
    for (int r = 0; r < 4; ++r) {
      float m = fmaxf(fmaxf(s[0][r], s[1][r]), fmaxf(s[2][r], s[3][r]));
#pragma unroll
      for (int off = 1; off < 16; off <<= 1) m = fmaxf(m, __shfl_xor(m, off));
      rm[r] = m;
    }
    bool small = (rm[0] - mrow[0] <= 8.f) && (rm[1] - mrow[1] <= 8.f) &&
                 (rm[2] - mrow[2] <= 8.f) && (rm[3] - mrow[3] <= 8.f);
    if (__all(small)) {
      // keep old max; P bounded by e^8, fine in bf16/f32
      float rsum[4] = {0.f, 0.f, 0.f, 0.f};
#pragma unroll
      for (int kt = 0; kt < 4; ++kt)
#pragma unroll
        for (int r = 0; r < 4; ++r) {
          float p = __expf(s[kt][r] - mrow[r]);
          s[kt][r] = p;
          rsum[r] += p;
        }
#pragma unroll
      for (int r = 0; r < 4; ++r) {
#pragma unroll
        for (int off = 1; off < 16; off <<= 1) rsum[r] += __shfl_xor(rsum[r], off);
        lrow[r] += rsum[r];
      }
    } else {
      float mnew[4], scl[4], rsum[4];
#pragma unroll
      for (int r = 0; r < 4; ++r) {
        mnew[r] = fmaxf(mrow[r], rm[r]);
        scl[r] = __expf(mrow[r] - mnew[r]);
        rsum[r] = 0.f;
      }
#pragma unroll
      for (int kt = 0; kt < 4; ++kt)
#pragma unroll
        for (int r = 0; r < 4; ++r) {
          float p = __expf(s[kt][r] - mnew[r]);
          s[kt][r] = p;
          rsum[r] += p;
        }
#pragma unroll
      for (int r = 0; r < 4; ++r) {
#pragma unroll
        for (int off = 1; off < 16; off <<= 1) rsum[r] += __shfl_xor(rsum[r], off);
        lrow[r] = lrow[r] * scl[r] + rsum[r];
        mrow[r] = mnew[r];
      }
#pragma unroll
      for (int dt = 0; dt < 16; ++dt)
#pragma unroll
        for (int r = 0; r < 4; ++r) o[dt][r] *= scl[r];
    }
    // ---- P (D-layout) -> LDS -> A-layout fragments ----
#pragma unroll
    for (int kt = 0; kt < 4; ++kt)
#pragma unroll
      for (int r = 0; r < 4; ++r)
        Plds[(l4 << 2) + r][kt * 16 + l15] = (bf16)s[kt][r];
    bf16x8 pa[2];
#pragma unroll
    for (int kk2 = 0; kk2 < 2; ++kk2)
      pa[kk2] = *(const bf16x8*)&Plds[l15][kk2 * 32 + koff];
    // ---- O += P V : 4 groups of {8 batched loads -> 8 MFMAs} ----
#pragma unroll
    for (int g = 0; g < 4; ++g) {
      bf16x8 vf[8];
#pragma unroll
      for (int t = 0; t < 4; ++t) {
        const bf16* vbase = Vp + (size_t)((g * 4 + t) * 16 + l15) * 2048 + kb * 64 + koff;
        vf[t * 2] = *(const bf16x8*)(vbase);
        vf[t * 2 + 1] = *(const bf16x8*)(vbase + 32);
      }
#pragma unroll
      for (int t = 0; t < 4; ++t) {
        int dt = g * 4 + t;
        o[dt] = __builtin_amdgcn_mfma_f32_16x16x32_bf16(pa[0], vf[t * 2], o[dt], 0, 0, 0);
        o[dt] = __builtin_amdgcn_mfma_f32_16x16x32_bf16(pa[1], vf[t * 2 + 1], o[dt], 0, 0, 0);
      }
    }
  }
  // epilogue
  float rcp[4];
#pragma unroll
  for (int r = 0; r < 4; ++r) rcp[r] = 1.0f / lrow[r];
#pragma unroll
  for (int dt = 0; dt < 16; ++dt)
#pragma unroll
    for (int r = 0; r < 4; ++r) {
      int qg = q0 + (l4 << 2) + r;
      Out[(size_t)(b * 2048 + qg) * 2048 + h * 256 + dt * 16 + l15] =
          (bf16)(o[dt][r] * rcp[r]);
    }
}

// ---------------- launch ----------------
extern "C" void kernel_launch(void* const* d_in, const int* in_sizes, int n_in,
                              void* d_out, int out_size, void* d_ws, size_t ws_size,
                              hipStream_t stream) {
  const float* hidden = (const float*)d_in[0];
  const float* q_w = (const float*)d_in[1];
  const float* k_w = (const float*)d_in[2];
  const float* v_w = (const float*)d_in[3];
  const float* o_w = (const float*)d_in[4];
  const float* qnw = (const float*)d_in[5];
  const float* knw = (const float*)d_in[6];

  char* ws = (char*)d_ws;
  const size_t MB = (size_t)1 << 20;
  bf16* h_bf  = (bf16*)(ws + 0 * MB);    // 16 MiB  [4096][2048]
  bf16* wqkv  = (bf16*)(ws + 16 * MB);   // 16 MiB  [4096][2048]
  bf16* wo    = (bf16*)(ws + 32 * MB);   // 8 MiB   [2048][2048]
  bf16* qkv   = (bf16*)(ws + 40 * MB);   // 32 MiB  [4096][4096]
  bf16* aout  = qkv;                     // reuse: [4096][2048]
  bf16* Qb    = (bf16*)(ws + 72 * MB);   // 16 MiB
  bf16* Kb    = (bf16*)(ws + 88 * MB);   // 8 MiB
  bf16* Vt    = (bf16*)(ws + 96 * MB);   // 8 MiB

  cast_bf16_kernel<<<8192, 256, 0, stream>>>(hidden, h_bf, 2097152);
  cast_bf16_kernel<<<4096, 256, 0, stream>>>(q_w, wqkv, 1048576);
  cast_bf16_kernel<<<2048, 256, 0, stream>>>(k_w, wqkv + (size_t)2048 * 2048, 524288);
  cast_bf16_kernel<<<2048, 256, 0, stream>>>(v_w, wqkv + (size_t)3072 * 2048, 524288);
  cast_bf16_kernel<<<4096, 256, 0, stream>>>(o_w, wo, 1048576);

  gemm_bt<1><<<dim3(32, 32), 256, 0, stream>>>(h_bf, wqkv, qkv, 4096, 4096, 2048);
  qknorm_kernel<<<16384, 256, 0, stream>>>(qkv, qnw, knw, Qb, Kb, Vt);
  attn_kernel<<<2048, 64, 0, stream>>>(Qb, Kb, Vt, aout);
  gemm_bt<0><<<dim3(16, 32), 256, 0, stream>>>(aout, wo, d_out, 4096, 2048, 2048);
}

// Round 6
// 566.167 us; speedup vs baseline: 1.3899x; 1.3776x over previous
//
#include <hip/hip_runtime.h>

typedef __bf16 bf16;
typedef __attribute__((ext_vector_type(4))) float f32x4;
typedef __attribute__((ext_vector_type(8))) __bf16 bf16x8;
typedef __attribute__((ext_vector_type(4))) __bf16 bf16x4;

#define HIDDEN 2048
#define L_SEQ 2048
#define NHEADS 8
#define NKV 4
#define HDIM 256

// async global->LDS 16B (dest must be linear: wave-uniform base + lane*16)
__device__ __forceinline__ void gload16(const bf16* g, void* l) {
  __builtin_amdgcn_global_load_lds((const __attribute__((address_space(1))) void*)g,
                                   (__attribute__((address_space(3))) void*)l, 16, 0, 0);
}

// ---------------- fp32 -> bf16 cast (vectorized) ----------------
__global__ __launch_bounds__(256) void cast_bf16_kernel(const float* __restrict__ in,
                                                        bf16* __restrict__ out, int n4) {
  int i = blockIdx.x * 256 + threadIdx.x;
  if (i >= n4) return;
  float4 v = ((const float4*)in)[i];
  bf16x4 o;
  o[0] = (bf16)v.x; o[1] = (bf16)v.y; o[2] = (bf16)v.z; o[3] = (bf16)v.w;
  ((bf16x4*)out)[i] = o;
}

// ---------------- GEMM: C = A @ B^T (unchanged) ----------------
template <int OUT_BF16>
__global__ __launch_bounds__(256) void gemm_bt(const bf16* __restrict__ A,
                                               const bf16* __restrict__ B,
                                               void* __restrict__ C,
                                               int M, int N, int K) {
  __shared__ __attribute__((aligned(16))) bf16 As[128 * 64];
  __shared__ __attribute__((aligned(16))) bf16 Bs[128 * 64];
  const int tid = threadIdx.x;
  const int lane = tid & 63;
  const int wid = tid >> 6;
  const int m0 = blockIdx.y * 128;
  const int n0 = blockIdx.x * 128;
  const int wm = (wid >> 1) * 64;
  const int wn = (wid & 1) * 64;

  const int srow = tid >> 3;
  const int scolb = (tid & 7) * 16;

  f32x4 acc[4][4];
#pragma unroll
  for (int i = 0; i < 4; ++i)
#pragma unroll
    for (int j = 0; j < 4; ++j) acc[i][j] = (f32x4){0.f, 0.f, 0.f, 0.f};

  for (int k0 = 0; k0 < K; k0 += 64) {
    __syncthreads();
#pragma unroll
    for (int c = 0; c < 4; ++c) {
      int row = c * 32 + srow;
      int gcol = (scolb ^ ((row & 7) << 4)) >> 1;
      gload16(A + (size_t)(m0 + row) * K + k0 + gcol, (char*)As + row * 128 + scolb);
      gload16(B + (size_t)(n0 + row) * K + k0 + gcol, (char*)Bs + row * 128 + scolb);
    }
    __syncthreads();
#pragma unroll
    for (int kk = 0; kk < 2; ++kk) {
      bf16x8 a[4], b[4];
      int colb = kk * 64 + (lane >> 4) * 16;
#pragma unroll
      for (int i = 0; i < 4; ++i) {
        int row = wm + i * 16 + (lane & 15);
        a[i] = *(const bf16x8*)((const char*)As + row * 128 + (colb ^ ((row & 7) << 4)));
      }
#pragma unroll
      for (int j = 0; j < 4; ++j) {
        int row = wn + j * 16 + (lane & 15);
        b[j] = *(const bf16x8*)((const char*)Bs + row * 128 + (colb ^ ((row & 7) << 4)));
      }
#pragma unroll
      for (int i = 0; i < 4; ++i)
#pragma unroll
        for (int j = 0; j < 4; ++j)
          acc[i][j] = __builtin_amdgcn_mfma_f32_16x16x32_bf16(a[i], b[j], acc[i][j], 0, 0, 0);
    }
  }
#pragma unroll
  for (int i = 0; i < 4; ++i)
#pragma unroll
    for (int j = 0; j < 4; ++j)
#pragma unroll
      for (int r = 0; r < 4; ++r) {
        int m = m0 + wm + i * 16 + ((lane >> 4) << 2) + r;
        int n = n0 + wn + j * 16 + (lane & 15);
        float v = acc[i][j][r];
        if (OUT_BF16)
          ((bf16*)C)[(size_t)m * N + n] = (bf16)v;
        else
          ((float*)C)[(size_t)m * N + n] = v;
      }
}

// ---------------- per-head RMSNorm + relayout (unchanged) ----------------
__global__ __launch_bounds__(256) void qknorm_kernel(const bf16* __restrict__ qkv,
                                                     const float* __restrict__ qnw,
                                                     const float* __restrict__ knw,
                                                     bf16* __restrict__ Q,
                                                     bf16* __restrict__ K,
                                                     bf16* __restrict__ Vt) {
  int w = threadIdx.x >> 6, lane = threadIdx.x & 63;
  int vec = blockIdx.x * 4 + w;
  int row = vec >> 4, sub = vec & 15;
  int b = row >> 11, l = row & 2047;
  const bf16* src = qkv + (size_t)row * 4096 + sub * 256 + lane * 4;
  bf16x4 v = *(const bf16x4*)src;
  float f[4];
#pragma unroll
  for (int j = 0; j < 4; ++j) f[j] = (float)v[j];

  if (sub < 12) {
    float ss = f[0] * f[0] + f[1] * f[1] + f[2] * f[2] + f[3] * f[3];
#pragma unroll
    for (int off = 1; off < 64; off <<= 1) ss += __shfl_xor(ss, off);
    float rs = rsqrtf(ss * (1.0f / 256.0f) + 1e-6f);
    if (sub < 8) {
      rs *= 0.0625f;
      bf16x4 o;
#pragma unroll
      for (int j = 0; j < 4; ++j) o[j] = (bf16)(f[j] * rs * qnw[lane * 4 + j]);
      *(bf16x4*)(Q + ((size_t)(b * 8 + sub) * 2048 + l) * 256 + lane * 4) = o;
    } else {
      bf16x4 o;
#pragma unroll
      for (int j = 0; j < 4; ++j) o[j] = (bf16)(f[j] * rs * knw[lane * 4 + j]);
      *(bf16x4*)(K + ((size_t)(b * 4 + (sub - 8)) * 2048 + l) * 256 + lane * 4) = o;
    }
  } else {
    bf16* dst = Vt + (size_t)(b * 4 + (sub - 12)) * 256 * 2048 + l;
#pragma unroll
    for (int j = 0; j < 4; ++j) dst[(size_t)(lane * 4 + j) * 2048] = v[j];
  }
}

// ---------------- flash attention (causal, GQA, LDS-staged K/V) ----------------
// 256 blocks = B(2) x KV(4) x qt(32). Block: 64 q-pos x 2 q-heads = 128 rows.
// 4 waves: wave w -> head_sub = w&1, row-half = w>>1 (32 rows each).
// K/V tiles (64 keys) double-buffered in LDS via global_load_lds:
//   Ks: [64][256] rows 512B, chunk-XOR swizzle c^=(row&7)
//   Vs: [256][64] rows 128B (d-major, from Vt), same swizzle
__global__ __launch_bounds__(256, 1) void attn_kernel(const bf16* __restrict__ Q,
                                                      const bf16* __restrict__ K,
                                                      const bf16* __restrict__ Vt,
                                                      bf16* __restrict__ Out) {
  extern __shared__ __attribute__((aligned(16))) char smem[];
  // layout: [0,32K) Ks buf0, [32K,64K) Ks buf1, [64K,96K) Vs buf0,
  //         [96K,128K) Vs buf1, [128K,146K) P tiles [4][32][72]
  bf16* PL = (bf16*)(smem + 131072);

  const int tid = threadIdx.x;
  const int lane = tid & 63;
  const int w = tid >> 6;
  const int head_sub = w & 1;
  const int half = w >> 1;
  const int bid = blockIdx.x;
  const int qt = bid & 31;
  const int kh = (bid >> 5) & 3;
  const int b = bid >> 7;
  const int head = kh * 2 + head_sub;
  const int q0 = qt * 64 + half * 32;  // this wave's first q row
  const int l15 = lane & 15;
  const int l4 = lane >> 4;
  const int koff = l4 * 8;
  bf16* Pw = PL + w * 32 * 72;

  const bf16* Qp = Q + ((size_t)(b * 8 + head) * 2048 + q0) * 256;
  const bf16* Kp = K + (size_t)(b * 4 + kh) * 2048 * 256;
  const bf16* Vp = Vt + (size_t)(b * 4 + kh) * 256 * 2048;

  // Q fragments: 32 rows x 256 (2 row-tiles), A-layout
  bf16x8 qf[2][8];
#pragma unroll
  for (int rt = 0; rt < 2; ++rt)
#pragma unroll
    for (int c = 0; c < 8; ++c)
      qf[rt][c] = *(const bf16x8*)(Qp + (size_t)(rt * 16 + l15) * 256 + c * 32 + koff);

  f32x4 o[2][16];
#pragma unroll
  for (int rt = 0; rt < 2; ++rt)
#pragma unroll
    for (int dt = 0; dt < 16; ++dt) o[rt][dt] = (f32x4){0.f, 0.f, 0.f, 0.f};
  float mrow[2][4], lrow[2][4];
#pragma unroll
  for (int rt = 0; rt < 2; ++rt)
#pragma unroll
    for (int r = 0; r < 4; ++r) { mrow[rt][r] = -__builtin_inff(); lrow[rt][r] = 0.f; }

  const int nkb = qt + 1;

  // ---- stage step 0 into buf0 ----
  {
#pragma unroll
    for (int i = 0; i < 8; ++i) {
      int cid = i * 256 + tid;
      int row = cid >> 5, c = cid & 31;
      gload16(Kp + (size_t)row * 256 + ((c ^ (row & 7)) << 3), smem + cid * 16);
    }
#pragma unroll
    for (int i = 0; i < 8; ++i) {
      int cid = i * 256 + tid;
      int row = cid >> 3, c = cid & 7;
      gload16(Vp + (size_t)row * 2048 + ((c ^ (row & 7)) << 3), smem + 65536 + cid * 16);
    }
  }
  __syncthreads();

  for (int kb = 0; kb < nkb; ++kb) {
    const int cur = kb & 1;
    const char* ksb = smem + cur * 32768;
    const char* vsb = smem + 65536 + cur * 32768;
    // ---- prefetch next tile into other buffer ----
    if (kb + 1 < nkb) {
      const int kv0 = (kb + 1) * 64;
      char* kd = smem + (cur ^ 1) * 32768;
      char* vd = smem + 65536 + (cur ^ 1) * 32768;
#pragma unroll
      for (int i = 0; i < 8; ++i) {
        int cid = i * 256 + tid;
        int row = cid >> 5, c = cid & 31;
        gload16(Kp + (size_t)(kv0 + row) * 256 + ((c ^ (row & 7)) << 3), kd + cid * 16);
      }
#pragma unroll
      for (int i = 0; i < 8; ++i) {
        int cid = i * 256 + tid;
        int row = cid >> 3, c = cid & 7;
        gload16(Vp + (size_t)row * 2048 + kv0 + ((c ^ (row & 7)) << 3), vd + cid * 16);
      }
    }

    // ---- S = Q K^T : 32 q-rows x 64 keys ----
    f32x4 s[2][4];
#pragma unroll
    for (int rt = 0; rt < 2; ++rt)
#pragma unroll
      for (int kt = 0; kt < 4; ++kt) s[rt][kt] = (f32x4){0.f, 0.f, 0.f, 0.f};
#pragma unroll
    for (int kt = 0; kt < 4; ++kt) {
      int row = kt * 16 + l15;
      const char* kr = ksb + row * 512;
      bf16x8 kf[8];
#pragma unroll
      for (int kk = 0; kk < 8; ++kk) {
        int c = (kk * 4 + l4) ^ (row & 7);
        kf[kk] = *(const bf16x8*)(kr + c * 16);
      }
#pragma unroll
      for (int kk = 0; kk < 8; ++kk) {
        s[0][kt] = __builtin_amdgcn_mfma_f32_16x16x32_bf16(qf[0][kk], kf[kk], s[0][kt], 0, 0, 0);
        s[1][kt] = __builtin_amdgcn_mfma_f32_16x16x32_bf16(qf[1][kk], kf[kk], s[1][kt], 0, 0, 0);
      }
    }
    if (kb == nkb - 1) {  // diagonal block: causal mask
#pragma unroll
      for (int rt = 0; rt < 2; ++rt)
#pragma unroll
        for (int kt = 0; kt < 4; ++kt) {
          int key = kb * 64 + kt * 16 + l15;
#pragma unroll
          for (int r = 0; r < 4; ++r) {
            int qg = q0 + rt * 16 + (l4 << 2) + r;
            if (key > qg) s[rt][kt][r] = -__builtin_inff();
          }
        }
    }
    // ---- online softmax with defer-max ----
    float rm[2][4];
#pragma unroll
    for (int rt = 0; rt < 2; ++rt)
#pragma unroll
      for (int r = 0; r < 4; ++r) {
        float m = fmaxf(fmaxf(s[rt][0][r], s[rt][1][r]), fmaxf(s[rt][2][r], s[rt][3][r]));
#pragma unroll
        for (int off = 1; off < 16; off <<= 1) m = fmaxf(m, __shfl_xor(m, off));
        rm[rt][r] = m;
      }
    bool small = true;
#pragma unroll
    for (int rt = 0; rt < 2; ++rt)
#pragma unroll
      for (int r = 0; r < 4; ++r) small = small && (rm[rt][r] - mrow[rt][r] <= 8.f);
    if (__all(small)) {
#pragma unroll
      for (int rt = 0; rt < 2; ++rt) {
        float rsum[4] = {0.f, 0.f, 0.f, 0.f};
#pragma unroll
        for (int kt = 0; kt < 4; ++kt)
#pragma unroll
          for (int r = 0; r < 4; ++r) {
            float p = __expf(s[rt][kt][r] - mrow[rt][r]);
            s[rt][kt][r] = p;
            rsum[r] += p;
          }
#pragma unroll
        for (int r = 0; r < 4; ++r) {
#pragma unroll
          for (int off = 1; off < 16; off <<= 1) rsum[r] += __shfl_xor(rsum[r], off);
          lrow[rt][r] += rsum[r];
        }
      }
    } else {
#pragma unroll
      for (int rt = 0; rt < 2; ++rt) {
        float mnew[4], scl[4], rsum[4];
#pragma unroll
        for (int r = 0; r < 4; ++r) {
          mnew[r] = fmaxf(mrow[rt][r], rm[rt][r]);
          scl[r] = __expf(mrow[rt][r] - mnew[r]);
          rsum[r] = 0.f;
        }
#pragma unroll
        for (int kt = 0; kt < 4; ++kt)
#pragma unroll
          for (int r = 0; r < 4; ++r) {
            float p = __expf(s[rt][kt][r] - mnew[r]);
            s[rt][kt][r] = p;
            rsum[r] += p;
          }
#pragma unroll
        for (int r = 0; r < 4; ++r) {
#pragma unroll
          for (int off = 1; off < 16; off <<= 1) rsum[r] += __shfl_xor(rsum[r], off);
          lrow[rt][r] = lrow[rt][r] * scl[r] + rsum[r];
          mrow[rt][r] = mnew[r];
        }
#pragma unroll
        for (int dt = 0; dt < 16; ++dt)
#pragma unroll
          for (int r = 0; r < 4; ++r) o[rt][dt][r] *= scl[r];
      }
    }
    // ---- P -> LDS (wave-private) -> A-frags ----
#pragma unroll
    for (int rt = 0; rt < 2; ++rt)
#pragma unroll
      for (int kt = 0; kt < 4; ++kt)
#pragma unroll
        for (int r = 0; r < 4; ++r)
          Pw[(rt * 16 + (l4 << 2) + r) * 72 + kt * 16 + l15] = (bf16)s[rt][kt][r];
    bf16x8 pa[2][2];
#pragma unroll
    for (int rt = 0; rt < 2; ++rt)
#pragma unroll
      for (int kk2 = 0; kk2 < 2; ++kk2)
        pa[rt][kk2] = *(const bf16x8*)&Pw[(rt * 16 + l15) * 72 + kk2 * 32 + koff];
    // ---- O += P V (V frags from LDS, shared across row-tiles) ----
#pragma unroll
    for (int g = 0; g < 4; ++g) {
      bf16x8 vf[8];
#pragma unroll
      for (int t = 0; t < 4; ++t) {
        int row = (g * 4 + t) * 16 + l15;
        const char* vr = vsb + row * 128;
        int c0 = l4 ^ (row & 7);
        int c1 = (4 + l4) ^ (row & 7);
        vf[t * 2] = *(const bf16x8*)(vr + c0 * 16);
        vf[t * 2 + 1] = *(const bf16x8*)(vr + c1 * 16);
      }
#pragma unroll
      for (int t = 0; t < 4; ++t) {
        int dt = g * 4 + t;
#pragma unroll
        for (int rt = 0; rt < 2; ++rt) {
          o[rt][dt] = __builtin_amdgcn_mfma_f32_16x16x32_bf16(pa[rt][0], vf[t * 2], o[rt][dt], 0, 0, 0);
          o[rt][dt] = __builtin_amdgcn_mfma_f32_16x16x32_bf16(pa[rt][1], vf[t * 2 + 1], o[rt][dt], 0, 0, 0);
        }
      }
    }
    __syncthreads();  // all waves done with cur; prefetch (vmcnt) drained
  }
  // ---- epilogue ----
#pragma unroll
  for (int rt = 0; rt < 2; ++rt) {
    float rcp[4];
#pragma unroll
    for (int r = 0; r < 4; ++r) rcp[r] = 1.0f / lrow[rt][r];
#pragma unroll
    for (int dt = 0; dt < 16; ++dt)
#pragma unroll
      for (int r = 0; r < 4; ++r) {
        int qg = q0 + rt * 16 + (l4 << 2) + r;
        Out[(size_t)(b * 2048 + qg) * 2048 + head * 256 + dt * 16 + l15] =
            (bf16)(o[rt][dt][r] * rcp[r]);
      }
  }
}

// ---------------- launch ----------------
extern "C" void kernel_launch(void* const* d_in, const int* in_sizes, int n_in,
                              void* d_out, int out_size, void* d_ws, size_t ws_size,
                              hipStream_t stream) {
  const float* hidden = (const float*)d_in[0];
  const float* q_w = (const float*)d_in[1];
  const float* k_w = (const float*)d_in[2];
  const float* v_w = (const float*)d_in[3];
  const float* o_w = (const float*)d_in[4];
  const float* qnw = (const float*)d_in[5];
  const float* knw = (const float*)d_in[6];

  char* ws = (char*)d_ws;
  const size_t MB = (size_t)1 << 20;
  bf16* h_bf  = (bf16*)(ws + 0 * MB);    // 16 MiB  [4096][2048]
  bf16* wqkv  = (bf16*)(ws + 16 * MB);   // 16 MiB  [4096][2048]
  bf16* wo    = (bf16*)(ws + 32 * MB);   // 8 MiB   [2048][2048]
  bf16* qkv   = (bf16*)(ws + 40 * MB);   // 32 MiB  [4096][4096]
  bf16* aout  = qkv;                     // reuse: [4096][2048]
  bf16* Qb    = (bf16*)(ws + 72 * MB);   // 16 MiB
  bf16* Kb    = (bf16*)(ws + 88 * MB);   // 8 MiB
  bf16* Vt    = (bf16*)(ws + 96 * MB);   // 8 MiB

  cast_bf16_kernel<<<8192, 256, 0, stream>>>(hidden, h_bf, 2097152);
  cast_bf16_kernel<<<4096, 256, 0, stream>>>(q_w, wqkv, 1048576);
  cast_bf16_kernel<<<2048, 256, 0, stream>>>(k_w, wqkv + (size_t)2048 * 2048, 524288);
  cast_bf16_kernel<<<2048, 256, 0, stream>>>(v_w, wqkv + (size_t)3072 * 2048, 524288);
  cast_bf16_kernel<<<4096, 256, 0, stream>>>(o_w, wo, 1048576);

  gemm_bt<1><<<dim3(32, 32), 256, 0, stream>>>(h_bf, wqkv, qkv, 4096, 4096, 2048);
  qknorm_kernel<<<16384, 256, 0, stream>>>(qkv, qnw, knw, Qb, Kb, Vt);

  // attn: 149504 B dynamic LDS (2x32KB K + 2x32KB V + 18KB P)
  static const int ATTN_LDS = 149504;
  (void)hipFuncSetAttribute((const void*)attn_kernel,
                            hipFuncAttributeMaxDynamicSharedMemorySize, ATTN_LDS);
  attn_kernel<<<256, 256, ATTN_LDS, stream>>>(Qb, Kb, Vt, aout);

  gemm_bt<0><<<dim3(16, 32), 256, 0, stream>>>(aout, wo, d_out, 4096, 2048, 2048);
}

// Round 8
// 428.335 us; speedup vs baseline: 1.8372x; 1.3218x over previous
//
#include <hip/hip_runtime.h>

typedef __bf16 bf16;
typedef __attribute__((ext_vector_type(4))) float f32x4;
typedef __attribute__((ext_vector_type(8))) __bf16 bf16x8;
typedef __attribute__((ext_vector_type(4))) __bf16 bf16x4;

#define HIDDEN 2048
#define L_SEQ 2048
#define NHEADS 8
#define NKV 4
#define HDIM 256

// async global->LDS 16B (dest must be linear: wave-uniform base + lane*16)
__device__ __forceinline__ void gload16(const bf16* g, void* l) {
  __builtin_amdgcn_global_load_lds((const __attribute__((address_space(1))) void*)g,
                                   (__attribute__((address_space(3))) void*)l, 16, 0, 0);
}

// ---------------- fp32 -> bf16 cast (vectorized) ----------------
__global__ __launch_bounds__(256) void cast_bf16_kernel(const float* __restrict__ in,
                                                        bf16* __restrict__ out, int n4) {
  int i = blockIdx.x * 256 + threadIdx.x;
  if (i >= n4) return;
  float4 v = ((const float4*)in)[i];
  bf16x4 o;
  o[0] = (bf16)v.x; o[1] = (bf16)v.y; o[2] = (bf16)v.z; o[3] = (bf16)v.w;
  ((bf16x4*)out)[i] = o;
}

// ---------------- GEMM: C = A @ B^T (unchanged) ----------------
template <int OUT_BF16>
__global__ __launch_bounds__(256) void gemm_bt(const bf16* __restrict__ A,
                                               const bf16* __restrict__ B,
                                               void* __restrict__ C,
                                               int M, int N, int K) {
  __shared__ __attribute__((aligned(16))) bf16 As[128 * 64];
  __shared__ __attribute__((aligned(16))) bf16 Bs[128 * 64];
  const int tid = threadIdx.x;
  const int lane = tid & 63;
  const int wid = tid >> 6;
  const int m0 = blockIdx.y * 128;
  const int n0 = blockIdx.x * 128;
  const int wm = (wid >> 1) * 64;
  const int wn = (wid & 1) * 64;

  const int srow = tid >> 3;
  const int scolb = (tid & 7) * 16;

  f32x4 acc[4][4];
#pragma unroll
  for (int i = 0; i < 4; ++i)
#pragma unroll
    for (int j = 0; j < 4; ++j) acc[i][j] = (f32x4){0.f, 0.f, 0.f, 0.f};

  for (int k0 = 0; k0 < K; k0 += 64) {
    __syncthreads();
#pragma unroll
    for (int c = 0; c < 4; ++c) {
      int row = c * 32 + srow;
      int gcol = (scolb ^ ((row & 7) << 4)) >> 1;
      gload16(A + (size_t)(m0 + row) * K + k0 + gcol, (char*)As + row * 128 + scolb);
      gload16(B + (size_t)(n0 + row) * K + k0 + gcol, (char*)Bs + row * 128 + scolb);
    }
    __syncthreads();
#pragma unroll
    for (int kk = 0; kk < 2; ++kk) {
      bf16x8 a[4], b[4];
      int colb = kk * 64 + (lane >> 4) * 16;
#pragma unroll
      for (int i = 0; i < 4; ++i) {
        int row = wm + i * 16 + (lane & 15);
        a[i] = *(const bf16x8*)((const char*)As + row * 128 + (colb ^ ((row & 7) << 4)));
      }
#pragma unroll
      for (int j = 0; j < 4; ++j) {
        int row = wn + j * 16 + (lane & 15);
        b[j] = *(const bf16x8*)((const char*)Bs + row * 128 + (colb ^ ((row & 7) << 4)));
      }
#pragma unroll
      for (int i = 0; i < 4; ++i)
#pragma unroll
        for (int j = 0; j < 4; ++j)
          acc[i][j] = __builtin_amdgcn_mfma_f32_16x16x32_bf16(a[i], b[j], acc[i][j], 0, 0, 0);
    }
  }
#pragma unroll
  for (int i = 0; i < 4; ++i)
#pragma unroll
    for (int j = 0; j < 4; ++j)
#pragma unroll
      for (int r = 0; r < 4; ++r) {
        int m = m0 + wm + i * 16 + ((lane >> 4) << 2) + r;
        int n = n0 + wn + j * 16 + (lane & 15);
        float v = acc[i][j][r];
        if (OUT_BF16)
          ((bf16*)C)[(size_t)m * N + n] = (bf16)v;
        else
          ((float*)C)[(size_t)m * N + n] = v;
      }
}

// ---------------- per-head RMSNorm + relayout (unchanged) ----------------
__global__ __launch_bounds__(256) void qknorm_kernel(const bf16* __restrict__ qkv,
                                                     const float* __restrict__ qnw,
                                                     const float* __restrict__ knw,
                                                     bf16* __restrict__ Q,
                                                     bf16* __restrict__ K,
                                                     bf16* __restrict__ Vt) {
  int w = threadIdx.x >> 6, lane = threadIdx.x & 63;
  int vec = blockIdx.x * 4 + w;
  int row = vec >> 4, sub = vec & 15;
  int b = row >> 11, l = row & 2047;
  const bf16* src = qkv + (size_t)row * 4096 + sub * 256 + lane * 4;
  bf16x4 v = *(const bf16x4*)src;
  float f[4];
#pragma unroll
  for (int j = 0; j < 4; ++j) f[j] = (float)v[j];

  if (sub < 12) {
    float ss = f[0] * f[0] + f[1] * f[1] + f[2] * f[2] + f[3] * f[3];
#pragma unroll
    for (int off = 1; off < 64; off <<= 1) ss += __shfl_xor(ss, off);
    float rs = rsqrtf(ss * (1.0f / 256.0f) + 1e-6f);
    if (sub < 8) {
      rs *= 0.0625f;
      bf16x4 o;
#pragma unroll
      for (int j = 0; j < 4; ++j) o[j] = (bf16)(f[j] * rs * qnw[lane * 4 + j]);
      *(bf16x4*)(Q + ((size_t)(b * 8 + sub) * 2048 + l) * 256 + lane * 4) = o;
    } else {
      bf16x4 o;
#pragma unroll
      for (int j = 0; j < 4; ++j) o[j] = (bf16)(f[j] * rs * knw[lane * 4 + j]);
      *(bf16x4*)(K + ((size_t)(b * 4 + (sub - 8)) * 2048 + l) * 256 + lane * 4) = o;
    }
  } else {
    bf16* dst = Vt + (size_t)(b * 4 + (sub - 12)) * 256 * 2048 + l;
#pragma unroll
    for (int j = 0; j < 4; ++j) dst[(size_t)(lane * 4 + j) * 2048] = v[j];
  }
}

// ---------------- flash attention (causal, GQA, LDS-staged K/V) ----------------
// 256 blocks = B(2) x KV(4) x pair(32). Block processes TWO complementary
// 32-row q-tiles t = p and t = 63-p (nkb(t) = t/2+1; total = 33 for all p ->
// perfectly balanced). Tile covers 32 q-pos x 2 GQA heads = 64 rows.
// 4 waves: wave w -> head_sub = w&1, row-half = w>>1 (16 rows each; no spill).
// K/V double-buffered in LDS via global_load_lds (linear dest, pre-swizzled
// source, swizzled reads):
//   Ks: [64][256] rows 512B, chunk swizzle c^=(row&7)
//   Vs: [256][64] rows 128B (d-major from Vt), same swizzle
__global__ __launch_bounds__(256, 1) void attn_kernel(const bf16* __restrict__ Q,
                                                      const bf16* __restrict__ K,
                                                      const bf16* __restrict__ Vt,
                                                      bf16* __restrict__ Out) {
  extern __shared__ __attribute__((aligned(16))) char smem[];
  // [0,64K) Ks bufs, [64K,128K) Vs bufs, [128K,137K) P tiles [4][16][72]
  bf16* PL = (bf16*)(smem + 131072);

  const int tid = threadIdx.x;
  const int lane = tid & 63;
  const int w = tid >> 6;
  const int head_sub = w & 1;
  const int half = w >> 1;
  const int bid = blockIdx.x;
  const int p = bid & 31;
  const int kh = (bid >> 5) & 3;
  const int b = bid >> 7;
  const int head = kh * 2 + head_sub;
  const int l15 = lane & 15;
  const int l4 = lane >> 4;
  const int koff = l4 * 8;
  bf16* Pw = PL + w * 16 * 72;

  const bf16* Kp = K + (size_t)(b * 4 + kh) * 2048 * 256;
  const bf16* Vp = Vt + (size_t)(b * 4 + kh) * 256 * 2048;

#pragma unroll
  for (int ph = 0; ph < 2; ++ph) {
    const int t = ph ? 63 - p : p;
    const int nkb = (t >> 1) + 1;
    const int q0 = t * 32 + half * 16;  // this wave's first q row

    const bf16* Qp = Q + ((size_t)(b * 8 + head) * 2048 + q0) * 256;
    // Q fragments: 16 rows x 256, A-layout
    bf16x8 qf[8];
#pragma unroll
    for (int c = 0; c < 8; ++c)
      qf[c] = *(const bf16x8*)(Qp + (size_t)l15 * 256 + c * 32 + koff);

    f32x4 o[16];
#pragma unroll
    for (int dt = 0; dt < 16; ++dt) o[dt] = (f32x4){0.f, 0.f, 0.f, 0.f};
    float mrow[4], lrow[4];
#pragma unroll
    for (int r = 0; r < 4; ++r) { mrow[r] = -__builtin_inff(); lrow[r] = 0.f; }

    // ---- stage kb=0 into buf0 ----
#pragma unroll
    for (int i = 0; i < 8; ++i) {
      int cid = i * 256 + tid;
      int row = cid >> 5, c = cid & 31;
      gload16(Kp + (size_t)row * 256 + ((c ^ (row & 7)) << 3), smem + cid * 16);
    }
#pragma unroll
    for (int i = 0; i < 8; ++i) {
      int cid = i * 256 + tid;
      int row = cid >> 3, c = cid & 7;
      gload16(Vp + (size_t)row * 2048 + ((c ^ (row & 7)) << 3), smem + 65536 + cid * 16);
    }
    __syncthreads();

    for (int kb = 0; kb < nkb; ++kb) {
      const int cur = kb & 1;
      const char* ksb = smem + cur * 32768;
      const char* vsb = smem + 65536 + cur * 32768;
      // ---- prefetch next tile into other buffer ----
      if (kb + 1 < nkb) {
        const int kv0 = (kb + 1) * 64;
        char* kd = smem + (cur ^ 1) * 32768;
        char* vd = smem + 65536 + (cur ^ 1) * 32768;
#pragma unroll
        for (int i = 0; i < 8; ++i) {
          int cid = i * 256 + tid;
          int row = cid >> 5, c = cid & 31;
          gload16(Kp + (size_t)(kv0 + row) * 256 + ((c ^ (row & 7)) << 3), kd + cid * 16);
        }
#pragma unroll
        for (int i = 0; i < 8; ++i) {
          int cid = i * 256 + tid;
          int row = cid >> 3, c = cid & 7;
          gload16(Vp + (size_t)row * 2048 + kv0 + ((c ^ (row & 7)) << 3), vd + cid * 16);
        }
      }

      // ---- S = Q K^T : 16 q-rows x 64 keys ----
      f32x4 s[4];
#pragma unroll
      for (int kt = 0; kt < 4; ++kt) s[kt] = (f32x4){0.f, 0.f, 0.f, 0.f};
#pragma unroll
      for (int kt = 0; kt < 4; ++kt) {
        int row = kt * 16 + l15;
        const char* kr = ksb + row * 512;
        bf16x8 kf[8];
#pragma unroll
        for (int kk = 0; kk < 8; ++kk) {
          int c = (kk * 4 + l4) ^ (row & 7);
          kf[kk] = *(const bf16x8*)(kr + c * 16);
        }
#pragma unroll
        for (int kk = 0; kk < 8; ++kk)
          s[kt] = __builtin_amdgcn_mfma_f32_16x16x32_bf16(qf[kk], kf[kk], s[kt], 0, 0, 0);
      }
      if (kb == nkb - 1) {  // diagonal block: causal mask
#pragma unroll
        for (int kt = 0; kt < 4; ++kt) {
          int key = kb * 64 + kt * 16 + l15;
#pragma unroll
          for (int r = 0; r < 4; ++r) {
            int qg = q0 + (l4 << 2) + r;
            if (key > qg) s[kt][r] = -__builtin_inff();
          }
        }
      }
      // ---- online softmax with defer-max ----
      float rm[4];
#pragma unroll
      for (int r = 0; r < 4; ++r) {
        float m = fmaxf(fmaxf(s[0][r], s[1][r]), fmaxf(s[2][r], s[3][r]));
#pragma unroll
        for (int off = 1; off < 16; off <<= 1) m = fmaxf(m, __shfl_xor(m, off));
        rm[r] = m;
      }
      bool small = (rm[0] - mrow[0] <= 8.f) && (rm[1] - mrow[1] <= 8.f) &&
                   (rm[2] - mrow[2] <= 8.f) && (rm[3] - mrow[3] <= 8.f);
      if (__all(small)) {
        float rsum[4] = {0.f, 0.f, 0.f, 0.f};
#pragma unroll
        for (int kt = 0; kt < 4; ++kt)
#pragma unroll
          for (int r = 0; r < 4; ++r) {
            float pe = __expf(s[kt][r] - mrow[r]);
            s[kt][r] = pe;
            rsum[r] += pe;
          }
#pragma unroll
        for (int r = 0; r < 4; ++r) {
#pragma unroll
          for (int off = 1; off < 16; off <<= 1) rsum[r] += __shfl_xor(rsum[r], off);
          lrow[r] += rsum[r];
        }
      } else {
        float mnew[4], scl[4], rsum[4];
#pragma unroll
        for (int r = 0; r < 4; ++r) {
          mnew[r] = fmaxf(mrow[r], rm[r]);
          scl[r] = __expf(mrow[r] - mnew[r]);
          rsum[r] = 0.f;
        }
#pragma unroll
        for (int kt = 0; kt < 4; ++kt)
#pragma unroll
          for (int r = 0; r < 4; ++r) {
            float pe = __expf(s[kt][r] - mnew[r]);
            s[kt][r] = pe;
            rsum[r] += pe;
          }
#pragma unroll
        for (int r = 0; r < 4; ++r) {
#pragma unroll
          for (int off = 1; off < 16; off <<= 1) rsum[r] += __shfl_xor(rsum[r], off);
          lrow[r] = lrow[r] * scl[r] + rsum[r];
          mrow[r] = mnew[r];
        }
#pragma unroll
        for (int dt = 0; dt < 16; ++dt)
#pragma unroll
          for (int r = 0; r < 4; ++r) o[dt][r] *= scl[r];
      }
      // ---- P -> LDS (wave-private) -> A-frags ----
#pragma unroll
      for (int kt = 0; kt < 4; ++kt)
#pragma unroll
        for (int r = 0; r < 4; ++r)
          Pw[((l4 << 2) + r) * 72 + kt * 16 + l15] = (bf16)s[kt][r];
      bf16x8 pa[2];
#pragma unroll
      for (int kk2 = 0; kk2 < 2; ++kk2)
        pa[kk2] = *(const bf16x8*)&Pw[l15 * 72 + kk2 * 32 + koff];
      // ---- O += P V (V frags from LDS) ----
#pragma unroll
      for (int g = 0; g < 4; ++g) {
        bf16x8 vf[8];
#pragma unroll
        for (int tt = 0; tt < 4; ++tt) {
          int row = (g * 4 + tt) * 16 + l15;
          const char* vr = vsb + row * 128;
          int c0 = l4 ^ (row & 7);
          int c1 = (4 + l4) ^ (row & 7);
          vf[tt * 2] = *(const bf16x8*)(vr + c0 * 16);
          vf[tt * 2 + 1] = *(const bf16x8*)(vr + c1 * 16);
        }
#pragma unroll
        for (int tt = 0; tt < 4; ++tt) {
          int dt = g * 4 + tt;
          o[dt] = __builtin_amdgcn_mfma_f32_16x16x32_bf16(pa[0], vf[tt * 2], o[dt], 0, 0, 0);
          o[dt] = __builtin_amdgcn_mfma_f32_16x16x32_bf16(pa[1], vf[tt * 2 + 1], o[dt], 0, 0, 0);
        }
      }
      __syncthreads();  // all waves done with cur; prefetch (vmcnt) drained
    }
    // ---- epilogue for this tile ----
    float rcp[4];
#pragma unroll
    for (int r = 0; r < 4; ++r) rcp[r] = 1.0f / lrow[r];
#pragma unroll
    for (int dt = 0; dt < 16; ++dt)
#pragma unroll
      for (int r = 0; r < 4; ++r) {
        int qg = q0 + (l4 << 2) + r;
        Out[(size_t)(b * 2048 + qg) * 2048 + head * 256 + dt * 16 + l15] =
            (bf16)(o[dt][r] * rcp[r]);
      }
  }
}

// ---------------- launch ----------------
extern "C" void kernel_launch(void* const* d_in, const int* in_sizes, int n_in,
                              void* d_out, int out_size, void* d_ws, size_t ws_size,
                              hipStream_t stream) {
  const float* hidden = (const float*)d_in[0];
  const float* q_w = (const float*)d_in[1];
  const float* k_w = (const float*)d_in[2];
  const float* v_w = (const float*)d_in[3];
  const float* o_w = (const float*)d_in[4];
  const float* qnw = (const float*)d_in[5];
  const float* knw = (const float*)d_in[6];

  char* ws = (char*)d_ws;
  const size_t MB = (size_t)1 << 20;
  bf16* h_bf  = (bf16*)(ws + 0 * MB);    // 16 MiB  [4096][2048]
  bf16* wqkv  = (bf16*)(ws + 16 * MB);   // 16 MiB  [4096][2048]
  bf16* wo    = (bf16*)(ws + 32 * MB);   // 8 MiB   [2048][2048]
  bf16* qkv   = (bf16*)(ws + 40 * MB);   // 32 MiB  [4096][4096]
  bf16* aout  = qkv;                     // reuse: [4096][2048]
  bf16* Qb    = (bf16*)(ws + 72 * MB);   // 16 MiB
  bf16* Kb    = (bf16*)(ws + 88 * MB);   // 8 MiB
  bf16* Vt    = (bf16*)(ws + 96 * MB);   // 8 MiB

  cast_bf16_kernel<<<8192, 256, 0, stream>>>(hidden, h_bf, 2097152);
  cast_bf16_kernel<<<4096, 256, 0, stream>>>(q_w, wqkv, 1048576);
  cast_bf16_kernel<<<2048, 256, 0, stream>>>(k_w, wqkv + (size_t)2048 * 2048, 524288);
  cast_bf16_kernel<<<2048, 256, 0, stream>>>(v_w, wqkv + (size_t)3072 * 2048, 524288);
  cast_bf16_kernel<<<4096, 256, 0, stream>>>(o_w, wo, 1048576);

  gemm_bt<1><<<dim3(32, 32), 256, 0, stream>>>(h_bf, wqkv, qkv, 4096, 4096, 2048);
  qknorm_kernel<<<16384, 256, 0, stream>>>(qkv, qnw, knw, Qb, Kb, Vt);

  // attn: 140288 B dynamic LDS (2x32KB K + 2x32KB V + 9KB P)
  static const int ATTN_LDS = 140288;
  (void)hipFuncSetAttribute((const void*)attn_kernel,
                            hipFuncAttributeMaxDynamicSharedMemorySize, ATTN_LDS);
  attn_kernel<<<256, 256, ATTN_LDS, stream>>>(Qb, Kb, Vt, aout);

  gemm_bt<0><<<dim3(16, 32), 256, 0, stream>>>(aout, wo, d_out, 4096, 2048, 2048);
}